// Round 3
// baseline (205.935 us; speedup 1.0000x reference)
//
#include <hip/hip_runtime.h>
#include <hip/hip_bf16.h>

#define N_NODES 512
#define N_EDGES (512 * 512)
#define NBLK 256                 // sort blocks
#define EPB (N_EDGES / NBLK)     // 1024 edges per sort block

typedef __attribute__((ext_vector_type(2))) _Float16 half2v;

#if defined(__has_builtin)
#if __has_builtin(__builtin_amdgcn_fdot2)
#define FDOT2(a, b, c) __builtin_amdgcn_fdot2((a), (b), (c), false)
#endif
#endif
#ifndef FDOT2
static __device__ inline float fdot2_asm(half2v a, half2v b, float c) {
    float d;
    asm("v_dot2_f32_f16 %0, %1, %2, %3" : "=v"(d) : "v"(a), "v"(b), "v"(c));
    return d;
}
#define FDOT2(a, b, c) fdot2_asm((a), (b), (c))
#endif

static __device__ inline unsigned pack_h2(float x, float y) {
    union { _Float16 h[2]; unsigned u; } c;
    c.h[0] = (_Float16)x;
    c.h[1] = (_Float16)y;
    return c.u;
}
static __device__ inline half2v bits_h2(int b) {
    union { int i; half2v h; } c;
    c.i = b;
    return c.h;
}

// ---------------------------------------------------------------------------
// Deterministic counting sort by dst — NO device-scope atomics.
// count: per-block LDS histogram -> TRANSPOSED bcnt_t[bucket][block] so the
// colscan read loop is coalesced (the old layout made colscan do 256
// stride-2KB reads per block — fully uncoalesced, latency-bound).
// ---------------------------------------------------------------------------
__global__ __launch_bounds__(256) void count_kernel(const int* __restrict__ dst,
                                                    int* __restrict__ bcnt_t) {
    __shared__ int h[N_NODES];
    int tid = threadIdx.x;
    int b = blockIdx.x;
    h[tid] = 0;
    h[tid + 256] = 0;
    __syncthreads();
#pragma unroll
    for (int k = 0; k < EPB / 256; k++)
        atomicAdd(&h[dst[b * EPB + k * 256 + tid]], 1);
    __syncthreads();
    bcnt_t[tid * NBLK + b] = h[tid];                // scattered store (cheap)
    bcnt_t[(tid + 256) * NBLK + b] = h[tid + 256];
}

// colscan: one block per bucket t. Coalesced read of bcnt_t[t][b]; exclusive
// prefix over sort blocks -> pre[b][t] (scattered store); bucket total -> tot.
__global__ __launch_bounds__(NBLK) void colscan_kernel(const int* __restrict__ bcnt_t,
                                                       int* __restrict__ pre,
                                                       int* __restrict__ tot) {
    __shared__ int buf[NBLK];
    int t = blockIdx.x;
    int b = threadIdx.x;
    int v = bcnt_t[t * NBLK + b];                   // coalesced
    buf[b] = v;
    __syncthreads();
    for (int d = 1; d < NBLK; d <<= 1) {
        int add = (b >= d) ? buf[b - d] : 0;
        __syncthreads();
        buf[b] += add;
        __syncthreads();
    }
    pre[b * N_NODES + t] = buf[b] - v;              // scattered store (cheap)
    if (b == NBLK - 1) tot[t] = buf[b];
}

// offs: scan of 512 bucket totals -> offs[513]. Tiny.
__global__ __launch_bounds__(512) void offs_kernel(const int* __restrict__ tot,
                                                   int* __restrict__ offs) {
    __shared__ int buf[N_NODES];
    int t = threadIdx.x;
    int v = tot[t];
    buf[t] = v;
    __syncthreads();
    for (int d = 1; d < N_NODES; d <<= 1) {
        int add = (t >= d) ? buf[t - d] : 0;
        __syncthreads();
        buf[t] += add;
        __syncthreads();
    }
    offs[t + 1] = buf[t];
    if (t == 0) offs[0] = 0;
}

// scatter: LDS cursor seeded from offs[t] + pre[b][t]; LDS atomics only.
__global__ __launch_bounds__(256) void scatter_kernel(const int* __restrict__ src,
                                                      const int* __restrict__ dst,
                                                      const float* __restrict__ ea,
                                                      const int* __restrict__ pre,
                                                      const int* __restrict__ offs,
                                                      int4* __restrict__ ed4) {
    __shared__ int lcur[N_NODES];
    int tid = threadIdx.x;
    int b = blockIdx.x;
    lcur[tid] = offs[tid] + pre[b * N_NODES + tid];
    lcur[tid + 256] = offs[tid + 256] + pre[b * N_NODES + tid + 256];
    __syncthreads();
#pragma unroll
    for (int k = 0; k < EPB / 256; k++) {
        int e = b * EPB + k * 256 + tid;
        const float* a = ea + (size_t)e * 6;
        float a0 = a[0], a1 = a[1], a2 = a[2], a3 = a[3], a4 = a[4], a5 = a[5];
        int p = atomicAdd(&lcur[dst[e]], 1);
        int4 r;
        r.x = (int)pack_h2(a0, a1);
        r.y = (int)pack_h2(a2, a3);
        r.z = (int)pack_h2(a4, a5);
        r.w = src[e];
        ed4[p] = r;
    }
}

// ---------------------------------------------------------------------------
// NNConv edge pipeline, LDS-staged 2-phase:
//   prologue: load chunk0 -> regs (coalesced, 1 int4/lane)
//   loop:     ds_write chunk c; sync; issue global loads for chunk c+1 (their
//             results are consumed by NEXT iteration's ds_write — structurally
//             in flight across the whole consume phase, compiler-proof);
//             consume chunk c from LDS (uniform ds_read_b128 broadcast +
//             8-deep unrolled gather ILP); sync.
// SPLIT: block's threads form SPLIT groups of BLK/SPLIT lanes; group s
// processes edge substream {s, s+SPLIT, ...} of each chunk. Lets small-A
// layers (L1: A=36, L3: A=120) use all 4 waves of a 256-thread block.
// Cross-group partials combined via LDS atomicAdd, then one global
// atomicAdd per output column.
// ---------------------------------------------------------------------------
template <int CIN, int COUT, int OG, int BLK, int G, int SPLIT>
__global__ __launch_bounds__(BLK) void nnconv_edges(
    const float* __restrict__ hprev,  // [512, CIN]
    const int4* __restrict__ ed4,     // [E] sorted-by-dst edge records
    const int* __restrict__ offs,     // [513]
    const float* __restrict__ We,     // [6, CIN*COUT] fp32
    const float* __restrict__ be,     // [CIN*COUT]
    float* __restrict__ agg)          // [512, COUT] pre-zeroed
{
    constexpr int J = CIN * COUT;
    constexpr int OPL = COUT / OG;   // o-groups per input feature
    constexpr int A = CIN * OPL;     // active lanes per group
    constexpr int GRP = BLK / SPLIT; // threads per group
    constexpr int CH = 256;          // chunk: edge records staged in LDS

    __shared__ int4 ebuf[CH];
    __shared__ float lds_acc[J];

    const int n = blockIdx.x / G;
    const int g = blockIdx.x % G;
    const int tid = threadIdx.x;
    const int t = tid & (GRP - 1);   // lane within group
    const int s = tid / GRP;         // group id (edge substream)
    const bool act = (t < A);
    const int i = act ? t / OPL : 0;
    const int og = act ? (t % OPL) * OG : 0;

    half2v wrp[OG][3];
    float ber[OG], acc[OG];
#pragma unroll
    for (int k = 0; k < OG; k++) {
        acc[k] = 0.f;
        int j = i * COUT + og + k;
        if (act) {
            ber[k] = be[j];
#pragma unroll
            for (int tt = 0; tt < 3; tt++)
                wrp[k][tt] = bits_h2((int)pack_h2(We[(2 * tt) * J + j], We[(2 * tt + 1) * J + j]));
        } else {
            ber[k] = 0.f;
#pragma unroll
            for (int tt = 0; tt < 3; tt++) wrp[k][tt] = bits_h2(0);
        }
    }

    const int start = offs[n];
    const int end = offs[n + 1];
    const int len = end - start;
    const int per = (len + G - 1) / G;
    int p0 = start + g * per;
    int p1 = p0 + per;
    if (p0 > end) p0 = end;
    if (p1 > end) p1 = end;

    const float* hp_i = hprev + i;   // per-lane feature-column base

    int p = p0;
    int4 st;
    {
        int c0 = p1 - p0;
        if (c0 > CH) c0 = CH;
        if (tid < c0) st = ed4[p0 + tid];     // coalesced prologue load
    }
    while (p < p1) {
        int cnt = p1 - p;
        if (cnt > CH) cnt = CH;
        if (tid < cnt) ebuf[tid] = st;        // ds_write_b128
        __syncthreads();
        int np = p + cnt;
        if (np < p1) {                        // issue next chunk NOW; result
            int nc = p1 - np;                 // lands at next ds_write — in
            if (nc > CH) nc = CH;             // flight across whole consume
            if (tid < nc) st = ed4[np + tid];
        }
        // ---- consume chunk: group s takes edges k = s, s+SPLIT, ... ----
        int k = s;
        for (; k + 7 * SPLIT < cnt; k += 8 * SPLIT) {
            int4 e[8];
            float xg[8];
#pragma unroll
            for (int u = 0; u < 8; u++) e[u] = ebuf[k + u * SPLIT];  // uniform, broadcast
#pragma unroll
            for (int u = 0; u < 8; u++) xg[u] = hp_i[(e[u].w & (N_NODES - 1)) * CIN];
#pragma unroll
            for (int u = 0; u < 8; u++) {
                half2v e01 = bits_h2(e[u].x), e23 = bits_h2(e[u].y), e45 = bits_h2(e[u].z);
#pragma unroll
                for (int kk = 0; kk < OG; kk++) {
                    float z = FDOT2(e45, wrp[kk][2],
                            FDOT2(e23, wrp[kk][1],
                            FDOT2(e01, wrp[kk][0], ber[kk])));
                    acc[kk] = fmaf(xg[u], fmaxf(z, 0.f), acc[kk]);
                }
            }
        }
        for (; k < cnt; k += SPLIT) {
            int4 e = ebuf[k];
            float xv = hp_i[(e.w & (N_NODES - 1)) * CIN];
            half2v e01 = bits_h2(e.x), e23 = bits_h2(e.y), e45 = bits_h2(e.z);
#pragma unroll
            for (int kk = 0; kk < OG; kk++) {
                float z = FDOT2(e45, wrp[kk][2],
                        FDOT2(e23, wrp[kk][1],
                        FDOT2(e01, wrp[kk][0], ber[kk])));
                acc[kk] = fmaf(xv, fmaxf(z, 0.f), acc[kk]);
            }
        }
        __syncthreads();
        p = np;
    }

    // ---- combine: zero LDS, atomic per-thread partials, column reduce ----
    for (int j = tid; j < J; j += BLK) lds_acc[j] = 0.f;
    __syncthreads();
    if (act) {
#pragma unroll
        for (int kk = 0; kk < OG; kk++) atomicAdd(&lds_acc[i * COUT + og + kk], acc[kk]);
    }
    __syncthreads();
    if (tid < COUT) {
        float sum = 0.f;
#pragma unroll
        for (int ii = 0; ii < CIN; ii++) sum += lds_acc[ii * COUT + tid];
        atomicAdd(&agg[n * COUT + tid], sum);
    }
}

// ---------------------------------------------------------------------------
// Finalize: mean + root-weight + bias + relu
// ---------------------------------------------------------------------------
template <int CIN, int COUT>
__global__ __launch_bounds__(64) void nnconv_fin(const float* __restrict__ agg,
                                                 const int* __restrict__ offs,
                                                 const float* __restrict__ hprev,
                                                 const float* __restrict__ root,
                                                 const float* __restrict__ bias,
                                                 float* __restrict__ hout) {
    int n = blockIdx.x;
    int t = threadIdx.x;
    if (t >= COUT) return;
    int cnt = offs[n + 1] - offs[n];
    float inv = 1.f / fmaxf((float)cnt, 1.f);
    float v = agg[n * COUT + t] * inv;
#pragma unroll
    for (int i = 0; i < CIN; i++) v = fmaf(hprev[n * CIN + i], root[i * COUT + t], v);
    v += bias[t];
    hout[n * COUT + t] = fmaxf(v, 0.f);
}

// ---------------------------------------------------------------------------
// CBT: out[i,j] = sum_k |h3[i,k] - h3[j,k]|, h3 is [512,5]
// ---------------------------------------------------------------------------
__global__ __launch_bounds__(256) void cbt_kernel(const float* __restrict__ h3,
                                                  float* __restrict__ out) {
    __shared__ float lh[N_NODES * 5];
    int tid = threadIdx.x;
    for (int idx = tid; idx < N_NODES * 5; idx += 256) lh[idx] = h3[idx];
    __syncthreads();
    int i = blockIdx.x;
    float hi[5];
#pragma unroll
    for (int k = 0; k < 5; k++) hi[k] = lh[i * 5 + k];
    for (int j = tid; j < N_NODES; j += 256) {
        float sacc = 0.f;
#pragma unroll
        for (int k = 0; k < 5; k++) sacc += fabsf(hi[k] - lh[j * 5 + k]);
        out[i * N_NODES + j] = sacc;
    }
}

// ---------------------------------------------------------------------------
extern "C" void kernel_launch(void* const* d_in, const int* in_sizes, int n_in,
                              void* d_out, int out_size, void* d_ws, size_t ws_size,
                              hipStream_t stream) {
    const float* x = (const float*)d_in[0];
    const float* edge_attr = (const float*)d_in[1];
    const int* edge_index = (const int*)d_in[2];
    const float* We1 = (const float*)d_in[3];
    const float* be1 = (const float*)d_in[4];
    const float* root1 = (const float*)d_in[5];
    const float* b1 = (const float*)d_in[6];
    const float* We2 = (const float*)d_in[7];
    const float* be2 = (const float*)d_in[8];
    const float* root2 = (const float*)d_in[9];
    const float* b2 = (const float*)d_in[10];
    const float* We3 = (const float*)d_in[11];
    const float* be3 = (const float*)d_in[12];
    const float* root3 = (const float*)d_in[13];
    const float* b3 = (const float*)d_in[14];

    const int E = N_EDGES;
    const int* src = edge_index;
    const int* dst = edge_index + E;

    char* ws = (char*)d_ws;
    int* offs = (int*)(ws + 0);               // 513 ints
    int* tot = (int*)(ws + 2048);             // 512 ints (fits in offs pad)
    int* bcnt_t = (int*)(ws + 4096);          // 512*256 ints (transposed) -> ends 528384
    int* pre = (int*)(ws + 528384);           // 256*512 ints -> ends 1052672
    int4* ed4 = (int4*)(ws + 1052672);        // E*16B -> ends 5246976
    float* agg1 = (float*)(ws + 5246976);     // 512*36 -> 5320704
    float* agg2 = (float*)(ws + 5320704);     // 512*24 -> 5369856
    float* agg3 = (float*)(ws + 5369856);     // 512*5  -> 5380096
    float* h1 = (float*)(ws + 5380096);       // 512*36 -> 5453824
    float* h2 = (float*)(ws + 5453824);       // 512*24 -> 5502976
    float* h3 = (float*)(ws + 5502976);       // 512*5  -> 5513216

    hipMemsetAsync(agg1, 0, 5380096 - 5246976, stream);  // agg1+agg2+agg3

    count_kernel<<<NBLK, 256, 0, stream>>>(dst, bcnt_t);
    colscan_kernel<<<N_NODES, NBLK, 0, stream>>>(bcnt_t, pre, tot);
    offs_kernel<<<1, 512, 0, stream>>>(tot, offs);
    scatter_kernel<<<NBLK, 256, 0, stream>>>(src, dst, edge_attr, pre, offs, ed4);

    // All layers: BLK=256, G=4 -> 2048 blocks (8/CU), LDS-staged chunks.
    // L1: CIN=1, COUT=36 -> A=36, SPLIT=4 (4 waves x 4 edge substreams)
    nnconv_edges<1, 36, 1, 256, 4, 4><<<N_NODES * 4, 256, 0, stream>>>(x, ed4, offs, We1, be1, agg1);
    nnconv_fin<1, 36><<<N_NODES, 64, 0, stream>>>(agg1, offs, x, root1, b1, h1);

    // L2: CIN=36, COUT=24, OG=4 -> A=216, SPLIT=1
    nnconv_edges<36, 24, 4, 256, 4, 1><<<N_NODES * 4, 256, 0, stream>>>(h1, ed4, offs, We2, be2, agg2);
    nnconv_fin<36, 24><<<N_NODES, 64, 0, stream>>>(agg2, offs, h1, root2, b2, h2);

    // L3: CIN=24, COUT=5 -> A=120, SPLIT=2 (2 wave-pairs x 2 substreams)
    nnconv_edges<24, 5, 1, 256, 4, 2><<<N_NODES * 4, 256, 0, stream>>>(h2, ed4, offs, We3, be3, agg3);
    nnconv_fin<24, 5><<<N_NODES, 64, 0, stream>>>(agg3, offs, h2, root3, b3, h3);

    cbt_kernel<<<N_NODES, 256, 0, stream>>>(h3, (float*)d_out);
}